// Round 20
// baseline (179.417 us; speedup 1.0000x reference)
//
#include <hip/hip_runtime.h>
#include <math.h>

#define N_NODES 50000
#define IN_CH   512
#define HID     8
#define HEADS   8
#define C1      64      // HEADS*HID
#define OUT_CH  40
#define NEG_SLOPE 0.2f
#define NB      ((N_NODES + 255) / 256)   // 196 coarse buckets (dst>>8)
#define TILE    4096                      // edges per part block
#define CAP     16384                     // per-bucket capacity (mean 8163)
#define PACKW_BLOCKS 128                  // 512*64/256
#define GEMM1_BLOCKS ((N_NODES + 31) / 32)   // 1563

__device__ __forceinline__ float leaky(float v) { return fmaxf(v, NEG_SLOPE * v); }
// logits are tiny (|a| < ~0.1): native v_exp_f32 path is exact enough (<=2ulp)
__device__ __forceinline__ float fexp(float v) { return __expf(v); }

typedef __attribute__((ext_vector_type(8))) short short8;
typedef __attribute__((ext_vector_type(4))) short short4v;
typedef __attribute__((ext_vector_type(4))) float f32x4;

__device__ __forceinline__ unsigned short f2bf(float f) {
    unsigned u = __builtin_bit_cast(unsigned, f);
    u += 0x7FFFu + ((u >> 16) & 1u);          // round-to-nearest-even
    return (unsigned short)(u >> 16);
}
__device__ __forceinline__ float bf2f(unsigned short h) {
    unsigned u = ((unsigned)h) << 16;
    return __builtin_bit_cast(float, u);
}

// ---------------------------------------------------------------------------
// K-PRE (merged, independent roles): blocks 0..127 pack W1 into MFMA
// B-fragment bf16 hi/lo; blocks 128+ run the coarse edge partition.
// Cursors are zero-initialized by memset; part adds t*CAP locally.
// ---------------------------------------------------------------------------
__global__ __launch_bounds__(256) void k_pre(
    const float* __restrict__ W1, short* __restrict__ bph, short* __restrict__ bpl,
    const int* __restrict__ src, const int* __restrict__ dst, int E,
    int* __restrict__ coarseCur, unsigned int* __restrict__ pairs)
{
    __shared__ int  hist[256];
    __shared__ int  scn[256];
    __shared__ int  offs[256];
    __shared__ unsigned int  pairBuf[TILE];
    __shared__ unsigned char bktBuf[TILE];

    const int t = threadIdx.x;

    if (blockIdx.x < PACKW_BLOCKS) {
        // ---- packW role
        const int idx = blockIdx.x * 256 + t;
        const int k = idx >> 6, col = idx & 63;
        const float w = W1[idx];
        const unsigned short hi = f2bf(w);
        const unsigned short lo = f2bf(w - bf2f(hi));
        const int di = ((k >> 5) * 64 + col) * 32 + (k & 31);
        bph[di] = (short)hi;
        bpl[di] = (short)lo;
        return;
    }

    // ---- coarse partition role
    const int tileBase = (blockIdx.x - PACKW_BLOCKS) * TILE;
    const int n = min(TILE, E - tileBase);

    hist[t] = 0;
    __syncthreads();

    for (int e = t; e < n; e += 256)
        atomicAdd(&hist[dst[tileBase + e] >> 8], 1);
    __syncthreads();

    scn[t] = hist[t];
    __syncthreads();
    #pragma unroll
    for (int off = 1; off < 256; off <<= 1) {
        int xv = (t >= off) ? scn[t - off] : 0;
        __syncthreads();
        scn[t] += xv;
        __syncthreads();
    }

    {
        const int h  = hist[t];
        const int ls = scn[t] - h;
        int off = 0;
        if (h > 0) {
            const int gbase = t * CAP + atomicAdd(&coarseCur[t], h);
            off = gbase - ls;
        }
        offs[t] = off;
        hist[t] = ls;
    }
    __syncthreads();

    for (int e = t; e < n; e += 256) {
        const int s = src[tileBase + e];
        const int d = dst[tileBase + e];
        const int bkt = d >> 8;
        const int pos = atomicAdd(&hist[bkt], 1);
        pairBuf[pos] = (unsigned)s | ((unsigned)(d & 255) << 17);
        bktBuf[pos]  = (unsigned char)bkt;
    }
    __syncthreads();

    for (int i = t; i < n; i += 256)
        pairs[i + offs[bktBuf[i]]] = pairBuf[i];
}

// ---------------------------------------------------------------------------
// K-MID (merged, independent roles): blocks 0..GEMM1_BLOCKS-1 run gemm1 with
// DIRECT-LOAD A-fragments (each lane loads its own 32B of x straight from
// global, converts to bf16 hi/lo in registers -> NO staging LDS, NO barriers
// in the main loop, 16 independent k-steps for deep load pipelining).
// Blocks GEMM1_BLOCKS+ run the fine scatter.
// ---------------------------------------------------------------------------
__global__ __launch_bounds__(256) void k_mid(
    const float* __restrict__ x,
    const short* __restrict__ bph, const short* __restrict__ bpl,
    const float* __restrict__ attS, const float* __restrict__ attD,
    unsigned short* __restrict__ h1b, float* __restrict__ aS, float* __restrict__ aD,
    const int* __restrict__ coarseCur, const unsigned int* __restrict__ pairs,
    int* __restrict__ ssrc, int* __restrict__ cumS, int* __restrict__ cumE)
{
    __shared__ float smemf[32 * 68];     // houtf [32][68] / fine2 scratch

    const int tid = threadIdx.x;

    if (blockIdx.x >= GEMM1_BLOCKS) {
        // ---- fine scatter role
        int* hist = (int*)smemf;
        int* scn  = hist + 256;
        int* cur  = scn + 256;
        const int b = blockIdx.x - GEMM1_BLOCKS;
        const int t = tid;
        const int dbase = b << 8;
        const int nd = min(256, N_NODES - dbase);
        const int lo = b * CAP;
        const int hi = lo + coarseCur[b];

        hist[t] = 0;
        __syncthreads();
        for (int j = lo + t; j < hi; j += 256)
            atomicAdd(&hist[(pairs[j] >> 17) & 255], 1);
        __syncthreads();

        const int hv = hist[t];
        scn[t] = hv;
        __syncthreads();
        #pragma unroll
        for (int off = 1; off < 256; off <<= 1) {
            int xv = (t >= off) ? scn[t - off] : 0;
            __syncthreads();
            scn[t] += xv;
            __syncthreads();
        }
        if (t < nd) {
            cumS[dbase + t] = lo + scn[t] - hv;
            cumE[dbase + t] = lo + scn[t];
        }
        cur[t] = lo + scn[t] - hv;
        __syncthreads();

        for (int j = lo + t; j < hi; j += 256) {
            const unsigned int p = pairs[j];
            const int pos = atomicAdd(&cur[(p >> 17) & 255], 1);
            ssrc[pos] = (int)(p & 0x1FFFFu);
        }
        return;
    }

    // ---- gemm1 role (direct-load A)
    float* houtf = smemf;               // [32][68]

    const int lane = tid & 63;
    const int w    = tid >> 6;
    const int row_off = (w & 1) * 16;
    const int col_off = (w >> 1) * 32;
    const int rowBase = blockIdx.x * 32;

    const int l15 = lane & 15;
    const int kg  = lane >> 4;

    const int myRow = rowBase + row_off + l15;
    const bool rowOK = (myRow < N_NODES);
    const float* xrow = x + (size_t)(rowOK ? myRow : 0) * IN_CH + kg * 8;

    f32x4 acc0 = {0.f, 0.f, 0.f, 0.f};
    f32x4 acc1 = {0.f, 0.f, 0.f, 0.f};
    float psum = 0.f;

    #pragma unroll 4
    for (int kk = 0; kk < 16; ++kk) {
        float4 v0 = *(const float4*)(xrow + kk * 32);
        float4 v1 = *(const float4*)(xrow + kk * 32 + 4);
        if (!rowOK) {
            v0 = make_float4(0.f, 0.f, 0.f, 0.f);
            v1 = make_float4(0.f, 0.f, 0.f, 0.f);
        }
        const float vs[8] = {v0.x, v0.y, v0.z, v0.w, v1.x, v1.y, v1.z, v1.w};
        short8 ah, al;
        #pragma unroll
        for (int j = 0; j < 8; ++j) {
            const unsigned short h = f2bf(vs[j]);
            ah[j] = (short)h;
            al[j] = (short)f2bf(vs[j] - bf2f(h));
            psum += vs[j];
        }
        const int b0 = (kk * 64 + col_off + l15) * 32 + kg * 8;
        const int b1 = b0 + 16 * 32;
        const short8 bh0 = *(const short8*)(bph + b0);
        const short8 bl0 = *(const short8*)(bpl + b0);
        const short8 bh1 = *(const short8*)(bph + b1);
        const short8 bl1 = *(const short8*)(bpl + b1);
        acc0 = __builtin_amdgcn_mfma_f32_16x16x32_bf16(ah, bh0, acc0, 0, 0, 0);
        acc1 = __builtin_amdgcn_mfma_f32_16x16x32_bf16(ah, bh1, acc1, 0, 0, 0);
        acc0 = __builtin_amdgcn_mfma_f32_16x16x32_bf16(ah, bl0, acc0, 0, 0, 0);
        acc1 = __builtin_amdgcn_mfma_f32_16x16x32_bf16(ah, bl1, acc1, 0, 0, 0);
        acc0 = __builtin_amdgcn_mfma_f32_16x16x32_bf16(al, bh0, acc0, 0, 0, 0);
        acc1 = __builtin_amdgcn_mfma_f32_16x16x32_bf16(al, bh1, acc1, 0, 0, 0);
    }

    // rowsum[l15] = reduce psum over the 4 kg-lanes (xor 16, 32)
    psum += __shfl_xor(psum, 16, 64);
    psum += __shfl_xor(psum, 32, 64);

    // normalize + stash: lane's C/D rows are row_off + kg*4 + r, col l15
    #pragma unroll
    for (int r = 0; r < 4; ++r) {
        const float rs = fmaxf(__shfl(psum, kg * 4 + r, 64), 1e-8f);
        const int row = row_off + kg * 4 + r;
        houtf[row * 68 + col_off + l15]      = acc0[r] / rs;
        houtf[row * 68 + col_off + 16 + l15] = acc1[r] / rs;
    }
    __syncthreads();

    // coalesced h1 write (bf16)
    #pragma unroll
    for (int i = tid; i < 32 * 16; i += 256) {
        const int row = i >> 4, seg = i & 15;
        if (rowBase + row < N_NODES) {
            const float* hs = houtf + row * 68 + seg * 4;
            short4v o = { (short)f2bf(hs[0]), (short)f2bf(hs[1]),
                          (short)f2bf(hs[2]), (short)f2bf(hs[3]) };
            *(short4v*)(h1b + (size_t)(rowBase + row) * 64 + seg * 4) = o;
        }
    }

    // logits: thread = (row, head), from fp32 LDS copy
    {
        const int row = tid >> 3, hd = tid & 7;
        if (rowBase + row < N_NODES) {
            float vsl = 0.f, vdl = 0.f;
            #pragma unroll
            for (int e2 = 0; e2 < 8; ++e2) {
                const float hv = houtf[row * 68 + hd * 8 + e2];
                vsl = fmaf(hv, attS[hd * 8 + e2], vsl);
                vdl = fmaf(hv, attD[hd * 8 + e2], vdl);
            }
            aS[(size_t)(rowBase + row) * 8 + hd] = vsl;
            aD[(size_t)(rowBase + row) * 8 + hd] = vdl;
        }
    }
}

// ---------------------------------------------------------------------------
// K-AGG1F: wave per node; lane = (edge e = lane>>3, chunk c = lane&7).
// Superrounds of 32 edges (12 gathers in flight) + rounds of 8 + masked tail.
// FUSED epilogue: ELU -> LDS -> gemm2 (64x40 matvec) -> h2b + logits.
// ---------------------------------------------------------------------------
__global__ __launch_bounds__(256) void k_agg1f(
    const int* __restrict__ cumS, const int* __restrict__ cumE,
    const int* __restrict__ ssrc,
    const float* __restrict__ aS, const float* __restrict__ aD,
    const unsigned short* __restrict__ h1b, const float* __restrict__ b1,
    const float* __restrict__ W2,
    const float* __restrict__ attS2, const float* __restrict__ attD2,
    unsigned short* __restrict__ h2b, float* __restrict__ a2s, float* __restrict__ a2d)
{
    __shared__ float w2s[64 * 40];      // 10.0 KB
    __shared__ float hstage[4][64];     // ELU'd layer-1 rows, one per wave

    const int tid  = threadIdx.x;
    const int lane = tid & 63;
    const int w    = tid >> 6;
    const int node = __builtin_amdgcn_readfirstlane(blockIdx.x * 4 + w);
    const int e = lane >> 3;      // edge slot 0..7
    const int c = lane & 7;       // chunk == head

    // stage W2 (coalesced float4); visibility ordered by the post-loop barrier
    #pragma unroll
    for (int i = tid; i < 640; i += 256)
        ((float4*)w2s)[i] = ((const float4*)W2)[i];

    const int start = cumS[node];
    const int end   = cumE[node];

    const float aDn = aD[(size_t)node * 8 + c];
    float acc[8] = {0.f, 0.f, 0.f, 0.f, 0.f, 0.f, 0.f, 0.f};
    float den = 0.f;

    if (e == 0) {   // self loop handled by the e==0 lane group
        const float e0 = fexp(leaky(aS[(size_t)node * 8 + c] + aDn));
        const short8 hv = *(const short8*)(h1b + (size_t)node * 64 + c * 8);
        #pragma unroll
        for (int j = 0; j < 8; ++j)
            acc[j] = e0 * bf2f((unsigned short)hv[j]);
        den = e0;
    }

    int base = start;
    // superrounds: 32 edges, 12 gathers in flight
    for (; base + 32 <= end; base += 32) {
        const int s0 = ssrc[base + e];
        const int s1 = ssrc[base + 8 + e];
        const int s2 = ssrc[base + 16 + e];
        const int s3 = ssrc[base + 24 + e];
        const float aa0 = aS[(size_t)s0 * 8 + c];
        const float aa1 = aS[(size_t)s1 * 8 + c];
        const float aa2 = aS[(size_t)s2 * 8 + c];
        const float aa3 = aS[(size_t)s3 * 8 + c];
        const short8 h0 = *(const short8*)(h1b + ((size_t)s0 << 6) + c * 8);
        const short8 h1v = *(const short8*)(h1b + ((size_t)s1 << 6) + c * 8);
        const short8 h2v = *(const short8*)(h1b + ((size_t)s2 << 6) + c * 8);
        const short8 h3v = *(const short8*)(h1b + ((size_t)s3 << 6) + c * 8);
        const float w0 = fexp(leaky(aa0 + aDn));
        const float w1 = fexp(leaky(aa1 + aDn));
        const float w2 = fexp(leaky(aa2 + aDn));
        const float w3 = fexp(leaky(aa3 + aDn));
        #pragma unroll
        for (int j = 0; j < 8; ++j) {
            acc[j] = fmaf(w0, bf2f((unsigned short)h0[j]), acc[j]);
            acc[j] = fmaf(w1, bf2f((unsigned short)h1v[j]), acc[j]);
            acc[j] = fmaf(w2, bf2f((unsigned short)h2v[j]), acc[j]);
            acc[j] = fmaf(w3, bf2f((unsigned short)h3v[j]), acc[j]);
        }
        den += w0 + w1 + w2 + w3;
    }
    // single rounds of 8
    for (; base + 8 <= end; base += 8) {
        const int s = ssrc[base + e];
        const float aa = aS[(size_t)s * 8 + c];
        const short8 hv = *(const short8*)(h1b + ((size_t)s << 6) + c * 8);
        const float wv = fexp(leaky(aa + aDn));
        #pragma unroll
        for (int j = 0; j < 8; ++j)
            acc[j] = fmaf(wv, bf2f((unsigned short)hv[j]), acc[j]);
        den += wv;
    }
    if (base < end) {          // masked tail (1..7 edges)
        const int nb  = end - base;
        const int idx = base + (e < nb ? e : nb - 1);
        const int s   = ssrc[idx];
        float wv = fexp(leaky(aS[(size_t)s * 8 + c] + aDn));
        if (e >= nb) wv = 0.f;
        const short8 hv = *(const short8*)(h1b + ((size_t)s << 6) + c * 8);
        #pragma unroll
        for (int j = 0; j < 8; ++j)
            acc[j] = fmaf(wv, bf2f((unsigned short)hv[j]), acc[j]);
        den += wv;
    }

    // reduce over e-dimension (lanes with equal c)
    #pragma unroll
    for (int m = 8; m < 64; m <<= 1) {
        den += __shfl_xor(den, m, 64);
        #pragma unroll
        for (int j = 0; j < 8; ++j)
            acc[j] += __shfl_xor(acc[j], m, 64);
    }

    if (e == 0) {   // lanes 0..7: finalize channels c*8..c*8+7 -> LDS
        const float dinv = 1.f / (den + 1e-16f);
        #pragma unroll
        for (int j = 0; j < 8; ++j) {
            const float v = acc[j] * dinv + b1[c * 8 + j];
            hstage[w][c * 8 + j] = v > 0.f ? v : (__expf(v) - 1.f);
        }
    }
    __syncthreads();   // orders w2s staging AND hstage writes for all waves

    // ---- fused gemm2: lane j computes h2[node][j] = helu_row . W2[:,j]
    const int j = lane;
    float acc2 = 0.f;
    if (j < OUT_CH) {
        #pragma unroll
        for (int k = 0; k < 64; ++k)
            acc2 = fmaf(hstage[w][k], w2s[k * 40 + j], acc2);
    }
    float vs = (j < OUT_CH) ? acc2 * attS2[j] : 0.f;
    float vd = (j < OUT_CH) ? acc2 * attD2[j] : 0.f;
    #pragma unroll
    for (int off = 32; off; off >>= 1) {
        vs += __shfl_xor(vs, off, 64);
        vd += __shfl_xor(vd, off, 64);
    }
    if (j < OUT_CH) h2b[(size_t)node * 40 + j] = f2bf(acc2);
    if (j == 0) {
        a2s[node] = vs;
        a2d[node] = vd;
    }
}

// ---------------------------------------------------------------------------
// K-AGG2: wave per node; lane = (e = lane>>3, c = lane&7), chunks 0..4 carry
// channels (h2b stride 40). Superrounds of 32 + rounds of 8 + masked tail.
// Dead lanes (c>=5) accumulate junk that is never read (cheaper than guards).
// ---------------------------------------------------------------------------
__global__ __launch_bounds__(256) void k_agg2(
    const int* __restrict__ cumS, const int* __restrict__ cumE,
    const int* __restrict__ ssrc,
    const float* __restrict__ a2s, const float* __restrict__ a2d,
    const unsigned short* __restrict__ h2b, const float* __restrict__ b2,
    float* __restrict__ out)
{
    const int lane = threadIdx.x & 63;
    const int node = __builtin_amdgcn_readfirstlane(blockIdx.x * 4 + (threadIdx.x >> 6));
    const int e = lane >> 3;
    const int c = lane & 7;

    const int start = cumS[node];
    const int end   = cumE[node];

    const float aDd = a2d[node];
    float acc[8] = {0.f, 0.f, 0.f, 0.f, 0.f, 0.f, 0.f, 0.f};
    float den = 0.f;

    if (e == 0) {
        const float e0 = fexp(leaky(a2s[node] + aDd));
        const short8 hv = *(const short8*)(h2b + (size_t)node * 40 + c * 8);
        #pragma unroll
        for (int j = 0; j < 8; ++j)
            acc[j] = e0 * bf2f((unsigned short)hv[j]);
        den = e0;
    }

    int base = start;
    for (; base + 32 <= end; base += 32) {
        const int s0 = ssrc[base + e];
        const int s1 = ssrc[base + 8 + e];
        const int s2 = ssrc[base + 16 + e];
        const int s3 = ssrc[base + 24 + e];
        const float aa0 = a2s[s0];
        const float aa1 = a2s[s1];
        const float aa2 = a2s[s2];
        const float aa3 = a2s[s3];
        const short8 h0 = *(const short8*)(h2b + (size_t)s0 * 40 + c * 8);
        const short8 h1v = *(const short8*)(h2b + (size_t)s1 * 40 + c * 8);
        const short8 h2v = *(const short8*)(h2b + (size_t)s2 * 40 + c * 8);
        const short8 h3v = *(const short8*)(h2b + (size_t)s3 * 40 + c * 8);
        const float w0 = fexp(leaky(aa0 + aDd));
        const float w1 = fexp(leaky(aa1 + aDd));
        const float w2 = fexp(leaky(aa2 + aDd));
        const float w3 = fexp(leaky(aa3 + aDd));
        #pragma unroll
        for (int j = 0; j < 8; ++j) {
            acc[j] = fmaf(w0, bf2f((unsigned short)h0[j]), acc[j]);
            acc[j] = fmaf(w1, bf2f((unsigned short)h1v[j]), acc[j]);
            acc[j] = fmaf(w2, bf2f((unsigned short)h2v[j]), acc[j]);
            acc[j] = fmaf(w3, bf2f((unsigned short)h3v[j]), acc[j]);
        }
        den += w0 + w1 + w2 + w3;
    }
    for (; base + 8 <= end; base += 8) {
        const int s = ssrc[base + e];
        const float aa = a2s[s];
        const short8 hv = *(const short8*)(h2b + (size_t)s * 40 + c * 8);
        const float wv = fexp(leaky(aa + aDd));
        #pragma unroll
        for (int j = 0; j < 8; ++j)
            acc[j] = fmaf(wv, bf2f((unsigned short)hv[j]), acc[j]);
        den += wv;
    }
    if (base < end) {
        const int nb  = end - base;
        const int idx = base + (e < nb ? e : nb - 1);
        const int s   = ssrc[idx];
        float wv = fexp(leaky(a2s[s] + aDd));
        if (e >= nb) wv = 0.f;
        const short8 hv = *(const short8*)(h2b + (size_t)s * 40 + c * 8);
        #pragma unroll
        for (int j = 0; j < 8; ++j)
            acc[j] = fmaf(wv, bf2f((unsigned short)hv[j]), acc[j]);
        den += wv;
    }

    #pragma unroll
    for (int m = 8; m < 64; m <<= 1) {
        den += __shfl_xor(den, m, 64);
        #pragma unroll
        for (int j = 0; j < 8; ++j)
            acc[j] += __shfl_xor(acc[j], m, 64);
    }

    if (e == 0 && c < 5) {   // lanes 0..4 write channels c*8..c*8+7
        const float dinv = 1.f / (den + 1e-16f);
        float o[8];
        #pragma unroll
        for (int j = 0; j < 8; ++j)
            o[j] = acc[j] * dinv + b2[c * 8 + j];
        float4* dst0 = (float4*)(out + (size_t)node * OUT_CH + c * 8);
        dst0[0] = make_float4(o[0], o[1], o[2], o[3]);
        dst0[1] = make_float4(o[4], o[5], o[6], o[7]);
    }
}

// ---------------------------------------------------------------------------
extern "C" void kernel_launch(void* const* d_in, const int* in_sizes, int n_in,
                              void* d_out, int out_size, void* d_ws, size_t ws_size,
                              hipStream_t stream)
{
    const float* x     = (const float*)d_in[0];
    const int*   ei    = (const int*)d_in[1];
    const float* W1    = (const float*)d_in[2];
    const float* attS1 = (const float*)d_in[3];
    const float* attD1 = (const float*)d_in[4];
    const float* b1    = (const float*)d_in[5];
    const float* W2    = (const float*)d_in[6];
    const float* attS2 = (const float*)d_in[7];
    const float* attD2 = (const float*)d_in[8];
    const float* b2    = (const float*)d_in[9];

    const int E = in_sizes[1] / 2;
    const int* src = ei;
    const int* dst = ei + E;

    float* out = (float*)d_out;
    float* f = (float*)d_ws;
    float* aS1  = f;  f += (size_t)N_NODES * 8;
    float* aD1  = f;  f += (size_t)N_NODES * 8;
    float* a2s  = f;  f += (size_t)N_NODES;
    float* a2d  = f;  f += (size_t)N_NODES;
    unsigned short* h1b = (unsigned short*)f;  f += (size_t)N_NODES * 32;  // bf16 [N][64]
    unsigned short* h2b = (unsigned short*)f;  f += (size_t)N_NODES * 20 + 64;  // bf16 [N][40] (+pad)
    short* bph = (short*)f;  f += 16384;        // 512*64 shorts (64 KB)
    short* bpl = (short*)f;  f += 16384;
    unsigned int* pairs = (unsigned int*)f;  f += (size_t)NB * CAP;
    int* ip = (int*)f;
    int* coarseCur = ip;  ip += 256;
    int* cumS      = ip;  ip += N_NODES;
    int* cumE      = ip;  ip += N_NODES;
    int* ssrc      = ip;  ip += (size_t)NB * CAP;

    const int partBlocks = (E + TILE - 1) / TILE;

    // cursors zeroed (part adds the b*CAP base locally)
    hipMemsetAsync(coarseCur, 0, 256 * sizeof(int), stream);

    // ---- phase 1: packW || coarse partition (independent roles, one launch)
    k_pre<<<PACKW_BLOCKS + partBlocks, 256, 0, stream>>>(W1, bph, bpl,
                                                         src, dst, E, coarseCur, pairs);

    // ---- phase 2: gemm1 (direct-load MFMA) || fine scatter
    k_mid<<<GEMM1_BLOCKS + NB, 256, 0, stream>>>(x, bph, bpl, attS1, attD1,
                                                 h1b, aS1, aD1,
                                                 coarseCur, pairs, ssrc, cumS, cumE);

    // ---- layer-1 aggregation fused with layer-2 GEMM + logits
    k_agg1f<<<N_NODES / 4, 256, 0, stream>>>(cumS, cumE, ssrc, aS1, aD1, h1b, b1,
                                             W2, attS2, attD2, h2b, a2s, a2d);

    // ---- layer-2 aggregation
    k_agg2<<<N_NODES / 4, 256, 0, stream>>>(cumS, cumE, ssrc, a2s, a2d, h2b, b2, out);
}

// Round 21
// 173.924 us; speedup vs baseline: 1.0316x; 1.0316x over previous
//
#include <hip/hip_runtime.h>
#include <math.h>

#define N_NODES 50000
#define IN_CH   512
#define HID     8
#define HEADS   8
#define C1      64      // HEADS*HID
#define OUT_CH  40
#define NEG_SLOPE 0.2f
#define NB      ((N_NODES + 255) / 256)   // 196 coarse buckets (dst>>8)
#define TILE    4096                      // edges per part block
#define CAP     16384                     // per-bucket capacity (mean 8163)
#define PACKW_BLOCKS 128                  // 512*64/256
#define GEMM1_BLOCKS ((N_NODES + 31) / 32)   // 1563

__device__ __forceinline__ float leaky(float v) { return fmaxf(v, NEG_SLOPE * v); }
// logits are tiny (|a| < ~0.1): native v_exp_f32 path is exact enough (<=2ulp)
__device__ __forceinline__ float fexp(float v) { return __expf(v); }

typedef __attribute__((ext_vector_type(8))) short short8;
typedef __attribute__((ext_vector_type(4))) short short4v;
typedef __attribute__((ext_vector_type(4))) float f32x4;

__device__ __forceinline__ unsigned short f2bf(float f) {
    unsigned u = __builtin_bit_cast(unsigned, f);
    u += 0x7FFFu + ((u >> 16) & 1u);          // round-to-nearest-even
    return (unsigned short)(u >> 16);
}
__device__ __forceinline__ float bf2f(unsigned short h) {
    unsigned u = ((unsigned)h) << 16;
    return __builtin_bit_cast(float, u);
}

#define XH_STRIDE_B 272   // bytes per LDS row: 128 bf16 = 256B + 16 pad

// ---------------------------------------------------------------------------
// K-PRE (merged, independent roles): blocks 0..127 pack W1 into MFMA
// B-fragment bf16 hi/lo; blocks 128+ run the coarse edge partition.
// ---------------------------------------------------------------------------
__global__ __launch_bounds__(256) void k_pre(
    const float* __restrict__ W1, short* __restrict__ bph, short* __restrict__ bpl,
    const int* __restrict__ src, const int* __restrict__ dst, int E,
    int* __restrict__ coarseCur, unsigned int* __restrict__ pairs)
{
    __shared__ int  hist[256];
    __shared__ int  scn[256];
    __shared__ int  offs[256];
    __shared__ unsigned int  pairBuf[TILE];
    __shared__ unsigned char bktBuf[TILE];

    const int t = threadIdx.x;

    if (blockIdx.x < PACKW_BLOCKS) {
        // ---- packW role
        const int idx = blockIdx.x * 256 + t;
        const int k = idx >> 6, col = idx & 63;
        const float w = W1[idx];
        const unsigned short hi = f2bf(w);
        const unsigned short lo = f2bf(w - bf2f(hi));
        const int di = ((k >> 5) * 64 + col) * 32 + (k & 31);
        bph[di] = (short)hi;
        bpl[di] = (short)lo;
        return;
    }

    // ---- coarse partition role
    const int tileBase = (blockIdx.x - PACKW_BLOCKS) * TILE;
    const int n = min(TILE, E - tileBase);

    hist[t] = 0;
    __syncthreads();

    for (int e = t; e < n; e += 256)
        atomicAdd(&hist[dst[tileBase + e] >> 8], 1);
    __syncthreads();

    scn[t] = hist[t];
    __syncthreads();
    #pragma unroll
    for (int off = 1; off < 256; off <<= 1) {
        int xv = (t >= off) ? scn[t - off] : 0;
        __syncthreads();
        scn[t] += xv;
        __syncthreads();
    }

    {
        const int h  = hist[t];
        const int ls = scn[t] - h;
        int off = 0;
        if (h > 0) {
            const int gbase = t * CAP + atomicAdd(&coarseCur[t], h);
            off = gbase - ls;
        }
        offs[t] = off;
        hist[t] = ls;
    }
    __syncthreads();

    for (int e = t; e < n; e += 256) {
        const int s = src[tileBase + e];
        const int d = dst[tileBase + e];
        const int bkt = d >> 8;
        const int pos = atomicAdd(&hist[bkt], 1);
        pairBuf[pos] = (unsigned)s | ((unsigned)(d & 255) << 17);
        bktBuf[pos]  = (unsigned char)bkt;
    }
    __syncthreads();

    for (int i = t; i < n; i += 256)
        pairs[i + offs[bktBuf[i]]] = pairBuf[i];
}

// ---------------------------------------------------------------------------
// K-MID (merged): blocks 0..GEMM1_BLOCKS-1 run gemm1 with DOUBLE-BUFFERED
// staging: per chunk, barrier -> issue LOAD(c+1) -> MFMA(c) from buffer A
// (covers load flight) -> STAGE(c+1) into buffer B (consumes loads before
// the next barrier). Loads never cross a barrier -> no vmcnt drain stall.
// Blocks GEMM1_BLOCKS+ run the fine scatter.
// ---------------------------------------------------------------------------
__global__ __launch_bounds__(256) void k_mid(
    const float* __restrict__ x,
    const short* __restrict__ bph, const short* __restrict__ bpl,
    const float* __restrict__ attS, const float* __restrict__ attD,
    unsigned short* __restrict__ h1b, float* __restrict__ aS, float* __restrict__ aD,
    const int* __restrict__ coarseCur, const unsigned int* __restrict__ pairs,
    int* __restrict__ ssrc, int* __restrict__ cumS, int* __restrict__ cumE)
{
    __shared__ unsigned char smem[34944];
    // buf0: xh @0, xl @8704 ; buf1: xh @17408, xl @26112 ; rowsum @34816
    // houtf [32][68] fp32 aliases buf0 (8704 B)

    const int tid = threadIdx.x;

    if (blockIdx.x >= GEMM1_BLOCKS) {
        // ---- fine scatter role
        int* hist = (int*)smem;
        int* scn  = hist + 256;
        int* cur  = scn + 256;
        const int b = blockIdx.x - GEMM1_BLOCKS;
        const int t = tid;
        const int dbase = b << 8;
        const int nd = min(256, N_NODES - dbase);
        const int lo = b * CAP;
        const int hi = lo + coarseCur[b];

        hist[t] = 0;
        __syncthreads();
        for (int j = lo + t; j < hi; j += 256)
            atomicAdd(&hist[(pairs[j] >> 17) & 255], 1);
        __syncthreads();

        const int hv = hist[t];
        scn[t] = hv;
        __syncthreads();
        #pragma unroll
        for (int off = 1; off < 256; off <<= 1) {
            int xv = (t >= off) ? scn[t - off] : 0;
            __syncthreads();
            scn[t] += xv;
            __syncthreads();
        }
        if (t < nd) {
            cumS[dbase + t] = lo + scn[t] - hv;
            cumE[dbase + t] = lo + scn[t];
        }
        cur[t] = lo + scn[t] - hv;
        __syncthreads();

        for (int j = lo + t; j < hi; j += 256) {
            const unsigned int p = pairs[j];
            const int pos = atomicAdd(&cur[(p >> 17) & 255], 1);
            ssrc[pos] = (int)(p & 0x1FFFFu);
        }
        return;
    }

    // ---- gemm1 role (double-buffered staging)
    char* const bufh[2] = { (char*)smem,         (char*)smem + 17408 };
    char* const bufl[2] = { (char*)smem + 8704,  (char*)smem + 26112 };
    float* rowsum = (float*)(smem + 34816);        // [32]
    float* houtf  = (float*)smem;                  // [32][68] (aliases buf0)

    const int lane = tid & 63;
    const int w    = tid >> 6;
    const int row_off = (w & 1) * 16;
    const int col_off = (w >> 1) * 32;
    const int rowBase = blockIdx.x * 32;

    const int l15 = lane & 15;
    const int kg  = lane >> 4;
    const int a_off = (l15 + row_off) * XH_STRIDE_B + kg * 16;

    const int srow = tid >> 5;          // staging row-group 0..7
    const int sk4  = tid & 31;          // staging k4 slot

    f32x4 acc0 = {0.f, 0.f, 0.f, 0.f};
    f32x4 acc1 = {0.f, 0.f, 0.f, 0.f};
    float psum[4] = {0.f, 0.f, 0.f, 0.f};
    float4 va[4], vb[4];

    auto LOAD = [&](int c, float4 (&v)[4]) {
        #pragma unroll
        for (int i = 0; i < 4; ++i) {
            const int grow = rowBase + i * 8 + srow;
            v[i] = (grow < N_NODES)
                 ? *(const float4*)(x + (size_t)grow * IN_CH + c * 128 + sk4 * 4)
                 : make_float4(0.f, 0.f, 0.f, 0.f);
        }
    };
    auto STAGE = [&](float4 (&v)[4], int buf) {
        #pragma unroll
        for (int i = 0; i < 4; ++i) {
            const int row = i * 8 + srow;
            const unsigned short h0 = f2bf(v[i].x), h1u = f2bf(v[i].y),
                                 h2 = f2bf(v[i].z), h3  = f2bf(v[i].w);
            short4v hvv = { (short)h0, (short)h1u, (short)h2, (short)h3 };
            short4v lvv = { (short)f2bf(v[i].x - bf2f(h0)), (short)f2bf(v[i].y - bf2f(h1u)),
                            (short)f2bf(v[i].z - bf2f(h2)), (short)f2bf(v[i].w - bf2f(h3)) };
            *(short4v*)(bufh[buf] + row * XH_STRIDE_B + sk4 * 8) = hvv;
            *(short4v*)(bufl[buf] + row * XH_STRIDE_B + sk4 * 8) = lvv;
            psum[i] += v[i].x + v[i].y + v[i].z + v[i].w;
        }
    };
    auto MFMA = [&](int c, int buf) {
        #pragma unroll
        for (int kk2 = 0; kk2 < 4; ++kk2) {
            const int kk = c * 4 + kk2;
            const short8 ah = *(const short8*)(bufh[buf] + a_off + kk2 * 64);
            const short8 al = *(const short8*)(bufl[buf] + a_off + kk2 * 64);
            const int b0 = (kk * 64 + col_off + l15) * 32 + kg * 8;
            const int b1 = b0 + 16 * 32;
            const short8 bh0 = *(const short8*)(bph + b0);
            const short8 bl0 = *(const short8*)(bpl + b0);
            const short8 bh1 = *(const short8*)(bph + b1);
            const short8 bl1 = *(const short8*)(bpl + b1);
            acc0 = __builtin_amdgcn_mfma_f32_16x16x32_bf16(ah, bh0, acc0, 0, 0, 0);
            acc1 = __builtin_amdgcn_mfma_f32_16x16x32_bf16(ah, bh1, acc1, 0, 0, 0);
            acc0 = __builtin_amdgcn_mfma_f32_16x16x32_bf16(ah, bl0, acc0, 0, 0, 0);
            acc1 = __builtin_amdgcn_mfma_f32_16x16x32_bf16(ah, bl1, acc1, 0, 0, 0);
            acc0 = __builtin_amdgcn_mfma_f32_16x16x32_bf16(al, bh0, acc0, 0, 0, 0);
            acc1 = __builtin_amdgcn_mfma_f32_16x16x32_bf16(al, bh1, acc1, 0, 0, 0);
        }
    };

    LOAD(0, va);
    STAGE(va, 0);
    __syncthreads();              // buf0 ready
    LOAD(1, vb);                  // loads in flight under MFMA(0)
    MFMA(0, 0);
    STAGE(vb, 1);                 // consumes loads; writes buf1
    __syncthreads();              // buf1 ready; buf0 free
    LOAD(2, va);
    MFMA(1, 1);
    STAGE(va, 0);
    __syncthreads();              // buf0 ready; buf1 free
    LOAD(3, vb);
    MFMA(2, 0);
    STAGE(vb, 1);
    __syncthreads();              // buf1 ready
    MFMA(3, 1);

    // rowsum: register partials -> 32-lane butterfly -> one LDS store per row
    #pragma unroll
    for (int i = 0; i < 4; ++i) {
        float s = psum[i];
        #pragma unroll
        for (int off = 16; off; off >>= 1) s += __shfl_xor(s, off, 32);
        if (sk4 == 0) rowsum[i * 8 + srow] = s;
    }
    __syncthreads();              // rowsum visible; buf0 free for houtf

    #pragma unroll
    for (int r = 0; r < 4; ++r) {
        const int row = row_off + kg * 4 + r;   // C/D: row=(lane>>4)*4+reg
        const float rs = fmaxf(rowsum[row], 1e-8f);
        houtf[row * 68 + col_off + l15]      = acc0[r] / rs;
        houtf[row * 68 + col_off + 16 + l15] = acc1[r] / rs;
    }
    __syncthreads();

    // coalesced h1 write (bf16)
    #pragma unroll
    for (int i = tid; i < 32 * 16; i += 256) {
        const int row = i >> 4, seg = i & 15;
        if (rowBase + row < N_NODES) {
            const float* hs = houtf + row * 68 + seg * 4;
            short4v o = { (short)f2bf(hs[0]), (short)f2bf(hs[1]),
                          (short)f2bf(hs[2]), (short)f2bf(hs[3]) };
            *(short4v*)(h1b + (size_t)(rowBase + row) * 64 + seg * 4) = o;
        }
    }

    // logits: thread = (row, head), from fp32 LDS copy
    {
        const int row = tid >> 3, hd = tid & 7;
        if (rowBase + row < N_NODES) {
            float vsl = 0.f, vdl = 0.f;
            #pragma unroll
            for (int e2 = 0; e2 < 8; ++e2) {
                const float hv = houtf[row * 68 + hd * 8 + e2];
                vsl = fmaf(hv, attS[hd * 8 + e2], vsl);
                vdl = fmaf(hv, attD[hd * 8 + e2], vdl);
            }
            aS[(size_t)(rowBase + row) * 8 + hd] = vsl;
            aD[(size_t)(rowBase + row) * 8 + hd] = vdl;
        }
    }
}

// ---------------------------------------------------------------------------
// K-AGG1F: wave per node; lane = (edge e = lane>>3, chunk c = lane&7).
// Superrounds of 32 edges (12 gathers in flight) + rounds of 8 + masked tail.
// FUSED epilogue: ELU -> LDS -> gemm2 (64x40 matvec) -> h2b + logits.
// ---------------------------------------------------------------------------
__global__ __launch_bounds__(256) void k_agg1f(
    const int* __restrict__ cumS, const int* __restrict__ cumE,
    const int* __restrict__ ssrc,
    const float* __restrict__ aS, const float* __restrict__ aD,
    const unsigned short* __restrict__ h1b, const float* __restrict__ b1,
    const float* __restrict__ W2,
    const float* __restrict__ attS2, const float* __restrict__ attD2,
    unsigned short* __restrict__ h2b, float* __restrict__ a2s, float* __restrict__ a2d)
{
    __shared__ float w2s[64 * 40];      // 10.0 KB
    __shared__ float hstage[4][64];     // ELU'd layer-1 rows, one per wave

    const int tid  = threadIdx.x;
    const int lane = tid & 63;
    const int w    = tid >> 6;
    const int node = __builtin_amdgcn_readfirstlane(blockIdx.x * 4 + w);
    const int e = lane >> 3;      // edge slot 0..7
    const int c = lane & 7;       // chunk == head

    // stage W2 (coalesced float4); visibility ordered by the post-loop barrier
    #pragma unroll
    for (int i = tid; i < 640; i += 256)
        ((float4*)w2s)[i] = ((const float4*)W2)[i];

    const int start = cumS[node];
    const int end   = cumE[node];

    const float aDn = aD[(size_t)node * 8 + c];
    float acc[8] = {0.f, 0.f, 0.f, 0.f, 0.f, 0.f, 0.f, 0.f};
    float den = 0.f;

    if (e == 0) {   // self loop handled by the e==0 lane group
        const float e0 = fexp(leaky(aS[(size_t)node * 8 + c] + aDn));
        const short8 hv = *(const short8*)(h1b + (size_t)node * 64 + c * 8);
        #pragma unroll
        for (int j = 0; j < 8; ++j)
            acc[j] = e0 * bf2f((unsigned short)hv[j]);
        den = e0;
    }

    int base = start;
    // superrounds: 32 edges, 12 gathers in flight
    for (; base + 32 <= end; base += 32) {
        const int s0 = ssrc[base + e];
        const int s1 = ssrc[base + 8 + e];
        const int s2 = ssrc[base + 16 + e];
        const int s3 = ssrc[base + 24 + e];
        const float aa0 = aS[(size_t)s0 * 8 + c];
        const float aa1 = aS[(size_t)s1 * 8 + c];
        const float aa2 = aS[(size_t)s2 * 8 + c];
        const float aa3 = aS[(size_t)s3 * 8 + c];
        const short8 h0 = *(const short8*)(h1b + ((size_t)s0 << 6) + c * 8);
        const short8 h1v = *(const short8*)(h1b + ((size_t)s1 << 6) + c * 8);
        const short8 h2v = *(const short8*)(h1b + ((size_t)s2 << 6) + c * 8);
        const short8 h3v = *(const short8*)(h1b + ((size_t)s3 << 6) + c * 8);
        const float w0 = fexp(leaky(aa0 + aDn));
        const float w1 = fexp(leaky(aa1 + aDn));
        const float w2 = fexp(leaky(aa2 + aDn));
        const float w3 = fexp(leaky(aa3 + aDn));
        #pragma unroll
        for (int j = 0; j < 8; ++j) {
            acc[j] = fmaf(w0, bf2f((unsigned short)h0[j]), acc[j]);
            acc[j] = fmaf(w1, bf2f((unsigned short)h1v[j]), acc[j]);
            acc[j] = fmaf(w2, bf2f((unsigned short)h2v[j]), acc[j]);
            acc[j] = fmaf(w3, bf2f((unsigned short)h3v[j]), acc[j]);
        }
        den += w0 + w1 + w2 + w3;
    }
    // single rounds of 8
    for (; base + 8 <= end; base += 8) {
        const int s = ssrc[base + e];
        const float aa = aS[(size_t)s * 8 + c];
        const short8 hv = *(const short8*)(h1b + ((size_t)s << 6) + c * 8);
        const float wv = fexp(leaky(aa + aDn));
        #pragma unroll
        for (int j = 0; j < 8; ++j)
            acc[j] = fmaf(wv, bf2f((unsigned short)hv[j]), acc[j]);
        den += wv;
    }
    if (base < end) {          // masked tail (1..7 edges)
        const int nb  = end - base;
        const int idx = base + (e < nb ? e : nb - 1);
        const int s   = ssrc[idx];
        float wv = fexp(leaky(aS[(size_t)s * 8 + c] + aDn));
        if (e >= nb) wv = 0.f;
        const short8 hv = *(const short8*)(h1b + ((size_t)s << 6) + c * 8);
        #pragma unroll
        for (int j = 0; j < 8; ++j)
            acc[j] = fmaf(wv, bf2f((unsigned short)hv[j]), acc[j]);
        den += wv;
    }

    // reduce over e-dimension (lanes with equal c)
    #pragma unroll
    for (int m = 8; m < 64; m <<= 1) {
        den += __shfl_xor(den, m, 64);
        #pragma unroll
        for (int j = 0; j < 8; ++j)
            acc[j] += __shfl_xor(acc[j], m, 64);
    }

    if (e == 0) {   // lanes 0..7: finalize channels c*8..c*8+7 -> LDS
        const float dinv = 1.f / (den + 1e-16f);
        #pragma unroll
        for (int j = 0; j < 8; ++j) {
            const float v = acc[j] * dinv + b1[c * 8 + j];
            hstage[w][c * 8 + j] = v > 0.f ? v : (__expf(v) - 1.f);
        }
    }
    __syncthreads();   // orders w2s staging AND hstage writes for all waves

    // ---- fused gemm2: lane j computes h2[node][j] = helu_row . W2[:,j]
    const int j = lane;
    float acc2 = 0.f;
    if (j < OUT_CH) {
        #pragma unroll
        for (int k = 0; k < 64; ++k)
            acc2 = fmaf(hstage[w][k], w2s[k * 40 + j], acc2);
    }
    float vs = (j < OUT_CH) ? acc2 * attS2[j] : 0.f;
    float vd = (j < OUT_CH) ? acc2 * attD2[j] : 0.f;
    #pragma unroll
    for (int off = 32; off; off >>= 1) {
        vs += __shfl_xor(vs, off, 64);
        vd += __shfl_xor(vd, off, 64);
    }
    if (j < OUT_CH) h2b[(size_t)node * 40 + j] = f2bf(acc2);
    if (j == 0) {
        a2s[node] = vs;
        a2d[node] = vd;
    }
}

// ---------------------------------------------------------------------------
// K-AGG2: wave per node; lane = (e = lane>>3, c = lane&7), chunks 0..4 carry
// channels (h2b stride 40). Superrounds of 32 + rounds of 8 + masked tail.
// Dead lanes (c>=5) accumulate junk that is never read (cheaper than guards).
// ---------------------------------------------------------------------------
__global__ __launch_bounds__(256) void k_agg2(
    const int* __restrict__ cumS, const int* __restrict__ cumE,
    const int* __restrict__ ssrc,
    const float* __restrict__ a2s, const float* __restrict__ a2d,
    const unsigned short* __restrict__ h2b, const float* __restrict__ b2,
    float* __restrict__ out)
{
    const int lane = threadIdx.x & 63;
    const int node = __builtin_amdgcn_readfirstlane(blockIdx.x * 4 + (threadIdx.x >> 6));
    const int e = lane >> 3;
    const int c = lane & 7;

    const int start = cumS[node];
    const int end   = cumE[node];

    const float aDd = a2d[node];
    float acc[8] = {0.f, 0.f, 0.f, 0.f, 0.f, 0.f, 0.f, 0.f};
    float den = 0.f;

    if (e == 0) {
        const float e0 = fexp(leaky(a2s[node] + aDd));
        const short8 hv = *(const short8*)(h2b + (size_t)node * 40 + c * 8);
        #pragma unroll
        for (int j = 0; j < 8; ++j)
            acc[j] = e0 * bf2f((unsigned short)hv[j]);
        den = e0;
    }

    int base = start;
    for (; base + 32 <= end; base += 32) {
        const int s0 = ssrc[base + e];
        const int s1 = ssrc[base + 8 + e];
        const int s2 = ssrc[base + 16 + e];
        const int s3 = ssrc[base + 24 + e];
        const float aa0 = a2s[s0];
        const float aa1 = a2s[s1];
        const float aa2 = a2s[s2];
        const float aa3 = a2s[s3];
        const short8 h0 = *(const short8*)(h2b + (size_t)s0 * 40 + c * 8);
        const short8 h1v = *(const short8*)(h2b + (size_t)s1 * 40 + c * 8);
        const short8 h2v = *(const short8*)(h2b + (size_t)s2 * 40 + c * 8);
        const short8 h3v = *(const short8*)(h2b + (size_t)s3 * 40 + c * 8);
        const float w0 = fexp(leaky(aa0 + aDd));
        const float w1 = fexp(leaky(aa1 + aDd));
        const float w2 = fexp(leaky(aa2 + aDd));
        const float w3 = fexp(leaky(aa3 + aDd));
        #pragma unroll
        for (int j = 0; j < 8; ++j) {
            acc[j] = fmaf(w0, bf2f((unsigned short)h0[j]), acc[j]);
            acc[j] = fmaf(w1, bf2f((unsigned short)h1v[j]), acc[j]);
            acc[j] = fmaf(w2, bf2f((unsigned short)h2v[j]), acc[j]);
            acc[j] = fmaf(w3, bf2f((unsigned short)h3v[j]), acc[j]);
        }
        den += w0 + w1 + w2 + w3;
    }
    for (; base + 8 <= end; base += 8) {
        const int s = ssrc[base + e];
        const float aa = a2s[s];
        const short8 hv = *(const short8*)(h2b + (size_t)s * 40 + c * 8);
        const float wv = fexp(leaky(aa + aDd));
        #pragma unroll
        for (int j = 0; j < 8; ++j)
            acc[j] = fmaf(wv, bf2f((unsigned short)hv[j]), acc[j]);
        den += wv;
    }
    if (base < end) {
        const int nb  = end - base;
        const int idx = base + (e < nb ? e : nb - 1);
        const int s   = ssrc[idx];
        float wv = fexp(leaky(a2s[s] + aDd));
        if (e >= nb) wv = 0.f;
        const short8 hv = *(const short8*)(h2b + (size_t)s * 40 + c * 8);
        #pragma unroll
        for (int j = 0; j < 8; ++j)
            acc[j] = fmaf(wv, bf2f((unsigned short)hv[j]), acc[j]);
        den += wv;
    }

    #pragma unroll
    for (int m = 8; m < 64; m <<= 1) {
        den += __shfl_xor(den, m, 64);
        #pragma unroll
        for (int j = 0; j < 8; ++j)
            acc[j] += __shfl_xor(acc[j], m, 64);
    }

    if (e == 0 && c < 5) {   // lanes 0..4 write channels c*8..c*8+7
        const float dinv = 1.f / (den + 1e-16f);
        float o[8];
        #pragma unroll
        for (int j = 0; j < 8; ++j)
            o[j] = acc[j] * dinv + b2[c * 8 + j];
        float4* dst0 = (float4*)(out + (size_t)node * OUT_CH + c * 8);
        dst0[0] = make_float4(o[0], o[1], o[2], o[3]);
        dst0[1] = make_float4(o[4], o[5], o[6], o[7]);
    }
}

// ---------------------------------------------------------------------------
extern "C" void kernel_launch(void* const* d_in, const int* in_sizes, int n_in,
                              void* d_out, int out_size, void* d_ws, size_t ws_size,
                              hipStream_t stream)
{
    const float* x     = (const float*)d_in[0];
    const int*   ei    = (const int*)d_in[1];
    const float* W1    = (const float*)d_in[2];
    const float* attS1 = (const float*)d_in[3];
    const float* attD1 = (const float*)d_in[4];
    const float* b1    = (const float*)d_in[5];
    const float* W2    = (const float*)d_in[6];
    const float* attS2 = (const float*)d_in[7];
    const float* attD2 = (const float*)d_in[8];
    const float* b2    = (const float*)d_in[9];

    const int E = in_sizes[1] / 2;
    const int* src = ei;
    const int* dst = ei + E;

    float* out = (float*)d_out;
    float* f = (float*)d_ws;
    float* aS1  = f;  f += (size_t)N_NODES * 8;
    float* aD1  = f;  f += (size_t)N_NODES * 8;
    float* a2s  = f;  f += (size_t)N_NODES;
    float* a2d  = f;  f += (size_t)N_NODES;
    unsigned short* h1b = (unsigned short*)f;  f += (size_t)N_NODES * 32;  // bf16 [N][64]
    unsigned short* h2b = (unsigned short*)f;  f += (size_t)N_NODES * 20 + 64;  // bf16 [N][40] (+pad)
    short* bph = (short*)f;  f += 16384;        // 512*64 shorts (64 KB)
    short* bpl = (short*)f;  f += 16384;
    unsigned int* pairs = (unsigned int*)f;  f += (size_t)NB * CAP;
    int* ip = (int*)f;
    int* coarseCur = ip;  ip += 256;
    int* cumS      = ip;  ip += N_NODES;
    int* cumE      = ip;  ip += N_NODES;
    int* ssrc      = ip;  ip += (size_t)NB * CAP;

    const int partBlocks = (E + TILE - 1) / TILE;

    // cursors zeroed (part adds the b*CAP base locally)
    hipMemsetAsync(coarseCur, 0, 256 * sizeof(int), stream);

    // ---- phase 1: packW || coarse partition (independent roles, one launch)
    k_pre<<<PACKW_BLOCKS + partBlocks, 256, 0, stream>>>(W1, bph, bpl,
                                                         src, dst, E, coarseCur, pairs);

    // ---- phase 2: gemm1 (double-buffered MFMA) || fine scatter
    k_mid<<<GEMM1_BLOCKS + NB, 256, 0, stream>>>(x, bph, bpl, attS1, attD1,
                                                 h1b, aS1, aD1,
                                                 coarseCur, pairs, ssrc, cumS, cumE);

    // ---- layer-1 aggregation fused with layer-2 GEMM + logits
    k_agg1f<<<N_NODES / 4, 256, 0, stream>>>(cumS, cumE, ssrc, aS1, aD1, h1b, b1,
                                             W2, attS2, attD2, h2b, a2s, a2d);

    // ---- layer-2 aggregation
    k_agg2<<<N_NODES / 4, 256, 0, stream>>>(cumS, cumE, ssrc, a2s, a2d, h2b, b2, out);
}

// Round 22
// 162.510 us; speedup vs baseline: 1.1040x; 1.0702x over previous
//
#include <hip/hip_runtime.h>
#include <math.h>

#define N_NODES 50000
#define IN_CH   512
#define HID     8
#define HEADS   8
#define C1      64      // HEADS*HID
#define OUT_CH  40
#define NEG_SLOPE 0.2f
#define NB      ((N_NODES + 255) / 256)   // 196 coarse buckets (dst>>8)
#define TILE    4096                      // edges per part block
#define CAP     16384                     // per-bucket capacity (mean 8163)
#define PACKW_BLOCKS 128                  // 512*64/256
#define GEMM1_BLOCKS ((N_NODES + 31) / 32)   // 1563

__device__ __forceinline__ float leaky(float v) { return fmaxf(v, NEG_SLOPE * v); }
// logits are tiny (|a| < ~0.1): native v_exp_f32 path is exact enough (<=2ulp)
__device__ __forceinline__ float fexp(float v) { return __expf(v); }

typedef __attribute__((ext_vector_type(8))) short short8;
typedef __attribute__((ext_vector_type(4))) short short4v;
typedef __attribute__((ext_vector_type(4))) float f32x4;

__device__ __forceinline__ unsigned short f2bf(float f) {
    unsigned u = __builtin_bit_cast(unsigned, f);
    u += 0x7FFFu + ((u >> 16) & 1u);          // round-to-nearest-even
    return (unsigned short)(u >> 16);
}
__device__ __forceinline__ float bf2f(unsigned short h) {
    unsigned u = ((unsigned)h) << 16;
    return __builtin_bit_cast(float, u);
}

#define XH_STRIDE_B 272   // bytes per LDS row: 128 bf16 = 256B + 16 pad

// ---------------------------------------------------------------------------
// K-PRE (merged, independent roles): blocks 0..127 pack W1 into MFMA
// B-fragment bf16 hi/lo; blocks 128+ run the coarse edge partition.
// ---------------------------------------------------------------------------
__global__ __launch_bounds__(256) void k_pre(
    const float* __restrict__ W1, short* __restrict__ bph, short* __restrict__ bpl,
    const int* __restrict__ src, const int* __restrict__ dst, int E,
    int* __restrict__ coarseCur, unsigned int* __restrict__ pairs)
{
    __shared__ int  hist[256];
    __shared__ int  scn[256];
    __shared__ int  offs[256];
    __shared__ unsigned int  pairBuf[TILE];
    __shared__ unsigned char bktBuf[TILE];

    const int t = threadIdx.x;

    if (blockIdx.x < PACKW_BLOCKS) {
        // ---- packW role
        const int idx = blockIdx.x * 256 + t;
        const int k = idx >> 6, col = idx & 63;
        const float w = W1[idx];
        const unsigned short hi = f2bf(w);
        const unsigned short lo = f2bf(w - bf2f(hi));
        const int di = ((k >> 5) * 64 + col) * 32 + (k & 31);
        bph[di] = (short)hi;
        bpl[di] = (short)lo;
        return;
    }

    // ---- coarse partition role
    const int tileBase = (blockIdx.x - PACKW_BLOCKS) * TILE;
    const int n = min(TILE, E - tileBase);

    hist[t] = 0;
    __syncthreads();

    for (int e = t; e < n; e += 256)
        atomicAdd(&hist[dst[tileBase + e] >> 8], 1);
    __syncthreads();

    scn[t] = hist[t];
    __syncthreads();
    #pragma unroll
    for (int off = 1; off < 256; off <<= 1) {
        int xv = (t >= off) ? scn[t - off] : 0;
        __syncthreads();
        scn[t] += xv;
        __syncthreads();
    }

    {
        const int h  = hist[t];
        const int ls = scn[t] - h;
        int off = 0;
        if (h > 0) {
            const int gbase = t * CAP + atomicAdd(&coarseCur[t], h);
            off = gbase - ls;
        }
        offs[t] = off;
        hist[t] = ls;
    }
    __syncthreads();

    for (int e = t; e < n; e += 256) {
        const int s = src[tileBase + e];
        const int d = dst[tileBase + e];
        const int bkt = d >> 8;
        const int pos = atomicAdd(&hist[bkt], 1);
        pairBuf[pos] = (unsigned)s | ((unsigned)(d & 255) << 17);
        bktBuf[pos]  = (unsigned char)bkt;
    }
    __syncthreads();

    for (int i = t; i < n; i += 256)
        pairs[i + offs[bktBuf[i]]] = pairBuf[i];
}

// ---------------------------------------------------------------------------
// K-MID (merged): blocks 0..NB-1 run the FINE SCATTER (placed FIRST so they
// overlap gemm1's ramp instead of serializing in the dispatch tail);
// blocks NB.. run gemm1 (r19 structure: staged, software-pipelined loads).
// ---------------------------------------------------------------------------
__global__ __launch_bounds__(256) void k_mid(
    const float* __restrict__ x,
    const short* __restrict__ bph, const short* __restrict__ bpl,
    const float* __restrict__ attS, const float* __restrict__ attD,
    unsigned short* __restrict__ h1b, float* __restrict__ aS, float* __restrict__ aD,
    const int* __restrict__ coarseCur, const unsigned int* __restrict__ pairs,
    int* __restrict__ ssrc, int* __restrict__ cumS, int* __restrict__ cumE)
{
    __shared__ unsigned char smem[17536];

    const int tid = threadIdx.x;

    if (blockIdx.x < NB) {
        // ---- fine scatter role (FIRST: overlaps gemm1 ramp)
        int* hist = (int*)smem;
        int* scn  = hist + 256;
        int* cur  = scn + 256;
        const int b = blockIdx.x;
        const int t = tid;
        const int dbase = b << 8;
        const int nd = min(256, N_NODES - dbase);
        const int lo = b * CAP;
        const int hi = lo + coarseCur[b];

        hist[t] = 0;
        __syncthreads();
        for (int j = lo + t; j < hi; j += 256)
            atomicAdd(&hist[(pairs[j] >> 17) & 255], 1);
        __syncthreads();

        const int hv = hist[t];
        scn[t] = hv;
        __syncthreads();
        #pragma unroll
        for (int off = 1; off < 256; off <<= 1) {
            int xv = (t >= off) ? scn[t - off] : 0;
            __syncthreads();
            scn[t] += xv;
            __syncthreads();
        }
        if (t < nd) {
            cumS[dbase + t] = lo + scn[t] - hv;
            cumE[dbase + t] = lo + scn[t];
        }
        cur[t] = lo + scn[t] - hv;
        __syncthreads();

        for (int j = lo + t; j < hi; j += 256) {
            const unsigned int p = pairs[j];
            const int pos = atomicAdd(&cur[(p >> 17) & 255], 1);
            ssrc[pos] = (int)(p & 0x1FFFFu);
        }
        return;
    }

    // ---- gemm1 role (r19 structure)
    short* xh = (short*)smem;                      // [32] rows x 136 shorts
    short* xl = (short*)(smem + 8704);
    float* rowsum = (float*)(smem + 17408);        // [32]
    float* houtf  = (float*)smem;                  // [32][68] (aliases xh/xl)

    const int lane = tid & 63;
    const int w    = tid >> 6;
    const int row_off = (w & 1) * 16;
    const int col_off = (w >> 1) * 32;
    const int rowBase = (blockIdx.x - NB) * 32;

    const int l15 = lane & 15;
    const int kg  = lane >> 4;
    const int a_base = (l15 + row_off) * XH_STRIDE_B + kg * 16;

    const int srow = tid >> 5;          // staging row-group 0..7
    const int sk4  = tid & 31;          // staging k4 slot

    f32x4 acc0 = {0.f, 0.f, 0.f, 0.f};
    f32x4 acc1 = {0.f, 0.f, 0.f, 0.f};
    float psum[4] = {0.f, 0.f, 0.f, 0.f};
    float4 va[4], vb[4];

    auto LOAD = [&](int c, float4 (&v)[4]) {
        #pragma unroll
        for (int i = 0; i < 4; ++i) {
            const int grow = rowBase + i * 8 + srow;
            v[i] = (grow < N_NODES)
                 ? *(const float4*)(x + (size_t)grow * IN_CH + c * 128 + sk4 * 4)
                 : make_float4(0.f, 0.f, 0.f, 0.f);
        }
    };
    auto STAGE = [&](float4 (&v)[4]) {
        #pragma unroll
        for (int i = 0; i < 4; ++i) {
            const int row = i * 8 + srow;
            const unsigned short h0 = f2bf(v[i].x), h1u = f2bf(v[i].y),
                                 h2 = f2bf(v[i].z), h3  = f2bf(v[i].w);
            short4v hvv = { (short)h0, (short)h1u, (short)h2, (short)h3 };
            short4v lvv = { (short)f2bf(v[i].x - bf2f(h0)), (short)f2bf(v[i].y - bf2f(h1u)),
                            (short)f2bf(v[i].z - bf2f(h2)), (short)f2bf(v[i].w - bf2f(h3)) };
            *(short4v*)((char*)xh + row * XH_STRIDE_B + sk4 * 8) = hvv;
            *(short4v*)((char*)xl + row * XH_STRIDE_B + sk4 * 8) = lvv;
            psum[i] += v[i].x + v[i].y + v[i].z + v[i].w;
        }
    };
    auto MFMA = [&](int c) {
        #pragma unroll
        for (int kk2 = 0; kk2 < 4; ++kk2) {
            const int kk = c * 4 + kk2;
            const short8 ah = *(const short8*)((const char*)xh + a_base + kk2 * 64);
            const short8 al = *(const short8*)((const char*)xl + a_base + kk2 * 64);
            const int b0 = (kk * 64 + col_off + l15) * 32 + kg * 8;
            const int b1 = b0 + 16 * 32;
            const short8 bh0 = *(const short8*)(bph + b0);
            const short8 bl0 = *(const short8*)(bpl + b0);
            const short8 bh1 = *(const short8*)(bph + b1);
            const short8 bl1 = *(const short8*)(bpl + b1);
            acc0 = __builtin_amdgcn_mfma_f32_16x16x32_bf16(ah, bh0, acc0, 0, 0, 0);
            acc1 = __builtin_amdgcn_mfma_f32_16x16x32_bf16(ah, bh1, acc1, 0, 0, 0);
            acc0 = __builtin_amdgcn_mfma_f32_16x16x32_bf16(ah, bl0, acc0, 0, 0, 0);
            acc1 = __builtin_amdgcn_mfma_f32_16x16x32_bf16(ah, bl1, acc1, 0, 0, 0);
            acc0 = __builtin_amdgcn_mfma_f32_16x16x32_bf16(al, bh0, acc0, 0, 0, 0);
            acc1 = __builtin_amdgcn_mfma_f32_16x16x32_bf16(al, bh1, acc1, 0, 0, 0);
        }
    };

    LOAD(0, va);
    STAGE(va);
    __syncthreads();
    LOAD(1, vb);
    MFMA(0);
    __syncthreads();
    STAGE(vb);
    __syncthreads();
    LOAD(2, va);
    MFMA(1);
    __syncthreads();
    STAGE(va);
    __syncthreads();
    LOAD(3, vb);
    MFMA(2);
    __syncthreads();
    STAGE(vb);
    #pragma unroll
    for (int i = 0; i < 4; ++i) {
        float s = psum[i];
        #pragma unroll
        for (int off = 16; off; off >>= 1) s += __shfl_xor(s, off, 32);
        if (sk4 == 0) rowsum[i * 8 + srow] = s;
    }
    __syncthreads();
    MFMA(3);
    __syncthreads();

    #pragma unroll
    for (int r = 0; r < 4; ++r) {
        const int row = row_off + kg * 4 + r;   // C/D: row=(lane>>4)*4+reg
        const float rs = fmaxf(rowsum[row], 1e-8f);
        houtf[row * 68 + col_off + l15]      = acc0[r] / rs;
        houtf[row * 68 + col_off + 16 + l15] = acc1[r] / rs;
    }
    __syncthreads();

    // coalesced h1 write (bf16)
    #pragma unroll
    for (int i = tid; i < 32 * 16; i += 256) {
        const int row = i >> 4, seg = i & 15;
        if (rowBase + row < N_NODES) {
            const float* hs = houtf + row * 68 + seg * 4;
            short4v o = { (short)f2bf(hs[0]), (short)f2bf(hs[1]),
                          (short)f2bf(hs[2]), (short)f2bf(hs[3]) };
            *(short4v*)(h1b + (size_t)(rowBase + row) * 64 + seg * 4) = o;
        }
    }

    // logits: thread = (row, head), from fp32 LDS copy
    {
        const int row = tid >> 3, hd = tid & 7;
        if (rowBase + row < N_NODES) {
            float vsl = 0.f, vdl = 0.f;
            #pragma unroll
            for (int e2 = 0; e2 < 8; ++e2) {
                const float hv = houtf[row * 68 + hd * 8 + e2];
                vsl = fmaf(hv, attS[hd * 8 + e2], vsl);
                vdl = fmaf(hv, attD[hd * 8 + e2], vdl);
            }
            aS[(size_t)(rowBase + row) * 8 + hd] = vsl;
            aD[(size_t)(rowBase + row) * 8 + hd] = vdl;
        }
    }
}

// ---------------------------------------------------------------------------
// K-AGG1F: wave per node; lane = (edge e = lane>>3, chunk c = lane&7).
// Superrounds of 32 edges (12 gathers in flight) + rounds of 8 + masked tail.
// FUSED epilogue: ELU -> LDS -> gemm2 (64x40 matvec) -> h2b + logits.
// ---------------------------------------------------------------------------
__global__ __launch_bounds__(256) void k_agg1f(
    const int* __restrict__ cumS, const int* __restrict__ cumE,
    const int* __restrict__ ssrc,
    const float* __restrict__ aS, const float* __restrict__ aD,
    const unsigned short* __restrict__ h1b, const float* __restrict__ b1,
    const float* __restrict__ W2,
    const float* __restrict__ attS2, const float* __restrict__ attD2,
    unsigned short* __restrict__ h2b, float* __restrict__ a2s, float* __restrict__ a2d)
{
    __shared__ float w2s[64 * 40];      // 10.0 KB
    __shared__ float hstage[4][64];     // ELU'd layer-1 rows, one per wave

    const int tid  = threadIdx.x;
    const int lane = tid & 63;
    const int w    = tid >> 6;
    const int node = __builtin_amdgcn_readfirstlane(blockIdx.x * 4 + w);
    const int e = lane >> 3;      // edge slot 0..7
    const int c = lane & 7;       // chunk == head

    // stage W2 (coalesced float4); visibility ordered by the post-loop barrier
    #pragma unroll
    for (int i = tid; i < 640; i += 256)
        ((float4*)w2s)[i] = ((const float4*)W2)[i];

    const int start = cumS[node];
    const int end   = cumE[node];

    const float aDn = aD[(size_t)node * 8 + c];
    float acc[8] = {0.f, 0.f, 0.f, 0.f, 0.f, 0.f, 0.f, 0.f};
    float den = 0.f;

    if (e == 0) {   // self loop handled by the e==0 lane group
        const float e0 = fexp(leaky(aS[(size_t)node * 8 + c] + aDn));
        const short8 hv = *(const short8*)(h1b + (size_t)node * 64 + c * 8);
        #pragma unroll
        for (int j = 0; j < 8; ++j)
            acc[j] = e0 * bf2f((unsigned short)hv[j]);
        den = e0;
    }

    int base = start;
    // superrounds: 32 edges, 12 gathers in flight
    for (; base + 32 <= end; base += 32) {
        const int s0 = ssrc[base + e];
        const int s1 = ssrc[base + 8 + e];
        const int s2 = ssrc[base + 16 + e];
        const int s3 = ssrc[base + 24 + e];
        const float aa0 = aS[(size_t)s0 * 8 + c];
        const float aa1 = aS[(size_t)s1 * 8 + c];
        const float aa2 = aS[(size_t)s2 * 8 + c];
        const float aa3 = aS[(size_t)s3 * 8 + c];
        const short8 h0 = *(const short8*)(h1b + ((size_t)s0 << 6) + c * 8);
        const short8 h1v = *(const short8*)(h1b + ((size_t)s1 << 6) + c * 8);
        const short8 h2v = *(const short8*)(h1b + ((size_t)s2 << 6) + c * 8);
        const short8 h3v = *(const short8*)(h1b + ((size_t)s3 << 6) + c * 8);
        const float w0 = fexp(leaky(aa0 + aDn));
        const float w1 = fexp(leaky(aa1 + aDn));
        const float w2 = fexp(leaky(aa2 + aDn));
        const float w3 = fexp(leaky(aa3 + aDn));
        #pragma unroll
        for (int j = 0; j < 8; ++j) {
            acc[j] = fmaf(w0, bf2f((unsigned short)h0[j]), acc[j]);
            acc[j] = fmaf(w1, bf2f((unsigned short)h1v[j]), acc[j]);
            acc[j] = fmaf(w2, bf2f((unsigned short)h2v[j]), acc[j]);
            acc[j] = fmaf(w3, bf2f((unsigned short)h3v[j]), acc[j]);
        }
        den += w0 + w1 + w2 + w3;
    }
    // single rounds of 8
    for (; base + 8 <= end; base += 8) {
        const int s = ssrc[base + e];
        const float aa = aS[(size_t)s * 8 + c];
        const short8 hv = *(const short8*)(h1b + ((size_t)s << 6) + c * 8);
        const float wv = fexp(leaky(aa + aDn));
        #pragma unroll
        for (int j = 0; j < 8; ++j)
            acc[j] = fmaf(wv, bf2f((unsigned short)hv[j]), acc[j]);
        den += wv;
    }
    if (base < end) {          // masked tail (1..7 edges)
        const int nb  = end - base;
        const int idx = base + (e < nb ? e : nb - 1);
        const int s   = ssrc[idx];
        float wv = fexp(leaky(aS[(size_t)s * 8 + c] + aDn));
        if (e >= nb) wv = 0.f;
        const short8 hv = *(const short8*)(h1b + ((size_t)s << 6) + c * 8);
        #pragma unroll
        for (int j = 0; j < 8; ++j)
            acc[j] = fmaf(wv, bf2f((unsigned short)hv[j]), acc[j]);
        den += wv;
    }

    // reduce over e-dimension (lanes with equal c)
    #pragma unroll
    for (int m = 8; m < 64; m <<= 1) {
        den += __shfl_xor(den, m, 64);
        #pragma unroll
        for (int j = 0; j < 8; ++j)
            acc[j] += __shfl_xor(acc[j], m, 64);
    }

    if (e == 0) {   // lanes 0..7: finalize channels c*8..c*8+7 -> LDS
        const float dinv = 1.f / (den + 1e-16f);
        #pragma unroll
        for (int j = 0; j < 8; ++j) {
            const float v = acc[j] * dinv + b1[c * 8 + j];
            hstage[w][c * 8 + j] = v > 0.f ? v : (__expf(v) - 1.f);
        }
    }
    __syncthreads();   // orders w2s staging AND hstage writes for all waves

    // ---- fused gemm2: lane j computes h2[node][j] = helu_row . W2[:,j]
    const int j = lane;
    float acc2 = 0.f;
    if (j < OUT_CH) {
        #pragma unroll
        for (int k = 0; k < 64; ++k)
            acc2 = fmaf(hstage[w][k], w2s[k * 40 + j], acc2);
    }
    float vs = (j < OUT_CH) ? acc2 * attS2[j] : 0.f;
    float vd = (j < OUT_CH) ? acc2 * attD2[j] : 0.f;
    #pragma unroll
    for (int off = 32; off; off >>= 1) {
        vs += __shfl_xor(vs, off, 64);
        vd += __shfl_xor(vd, off, 64);
    }
    if (j < OUT_CH) h2b[(size_t)node * 40 + j] = f2bf(acc2);
    if (j == 0) {
        a2s[node] = vs;
        a2d[node] = vd;
    }
}

// ---------------------------------------------------------------------------
// K-AGG2: wave per node; lane = (e = lane>>3, c = lane&7), chunks 0..4 carry
// channels (h2b stride 40). Superrounds of 32 + rounds of 8 + masked tail.
// Dead lanes (c>=5) accumulate junk that is never read (cheaper than guards).
// ---------------------------------------------------------------------------
__global__ __launch_bounds__(256) void k_agg2(
    const int* __restrict__ cumS, const int* __restrict__ cumE,
    const int* __restrict__ ssrc,
    const float* __restrict__ a2s, const float* __restrict__ a2d,
    const unsigned short* __restrict__ h2b, const float* __restrict__ b2,
    float* __restrict__ out)
{
    const int lane = threadIdx.x & 63;
    const int node = __builtin_amdgcn_readfirstlane(blockIdx.x * 4 + (threadIdx.x >> 6));
    const int e = lane >> 3;
    const int c = lane & 7;

    const int start = cumS[node];
    const int end   = cumE[node];

    const float aDd = a2d[node];
    float acc[8] = {0.f, 0.f, 0.f, 0.f, 0.f, 0.f, 0.f, 0.f};
    float den = 0.f;

    if (e == 0) {
        const float e0 = fexp(leaky(a2s[node] + aDd));
        const short8 hv = *(const short8*)(h2b + (size_t)node * 40 + c * 8);
        #pragma unroll
        for (int j = 0; j < 8; ++j)
            acc[j] = e0 * bf2f((unsigned short)hv[j]);
        den = e0;
    }

    int base = start;
    for (; base + 32 <= end; base += 32) {
        const int s0 = ssrc[base + e];
        const int s1 = ssrc[base + 8 + e];
        const int s2 = ssrc[base + 16 + e];
        const int s3 = ssrc[base + 24 + e];
        const float aa0 = a2s[s0];
        const float aa1 = a2s[s1];
        const float aa2 = a2s[s2];
        const float aa3 = a2s[s3];
        const short8 h0 = *(const short8*)(h2b + (size_t)s0 * 40 + c * 8);
        const short8 h1v = *(const short8*)(h2b + (size_t)s1 * 40 + c * 8);
        const short8 h2v = *(const short8*)(h2b + (size_t)s2 * 40 + c * 8);
        const short8 h3v = *(const short8*)(h2b + (size_t)s3 * 40 + c * 8);
        const float w0 = fexp(leaky(aa0 + aDd));
        const float w1 = fexp(leaky(aa1 + aDd));
        const float w2 = fexp(leaky(aa2 + aDd));
        const float w3 = fexp(leaky(aa3 + aDd));
        #pragma unroll
        for (int j = 0; j < 8; ++j) {
            acc[j] = fmaf(w0, bf2f((unsigned short)h0[j]), acc[j]);
            acc[j] = fmaf(w1, bf2f((unsigned short)h1v[j]), acc[j]);
            acc[j] = fmaf(w2, bf2f((unsigned short)h2v[j]), acc[j]);
            acc[j] = fmaf(w3, bf2f((unsigned short)h3v[j]), acc[j]);
        }
        den += w0 + w1 + w2 + w3;
    }
    for (; base + 8 <= end; base += 8) {
        const int s = ssrc[base + e];
        const float aa = a2s[s];
        const short8 hv = *(const short8*)(h2b + (size_t)s * 40 + c * 8);
        const float wv = fexp(leaky(aa + aDd));
        #pragma unroll
        for (int j = 0; j < 8; ++j)
            acc[j] = fmaf(wv, bf2f((unsigned short)hv[j]), acc[j]);
        den += wv;
    }
    if (base < end) {
        const int nb  = end - base;
        const int idx = base + (e < nb ? e : nb - 1);
        const int s   = ssrc[idx];
        float wv = fexp(leaky(a2s[s] + aDd));
        if (e >= nb) wv = 0.f;
        const short8 hv = *(const short8*)(h2b + (size_t)s * 40 + c * 8);
        #pragma unroll
        for (int j = 0; j < 8; ++j)
            acc[j] = fmaf(wv, bf2f((unsigned short)hv[j]), acc[j]);
        den += wv;
    }

    #pragma unroll
    for (int m = 8; m < 64; m <<= 1) {
        den += __shfl_xor(den, m, 64);
        #pragma unroll
        for (int j = 0; j < 8; ++j)
            acc[j] += __shfl_xor(acc[j], m, 64);
    }

    if (e == 0 && c < 5) {   // lanes 0..4 write channels c*8..c*8+7
        const float dinv = 1.f / (den + 1e-16f);
        float o[8];
        #pragma unroll
        for (int j = 0; j < 8; ++j)
            o[j] = acc[j] * dinv + b2[c * 8 + j];
        float4* dst0 = (float4*)(out + (size_t)node * OUT_CH + c * 8);
        dst0[0] = make_float4(o[0], o[1], o[2], o[3]);
        dst0[1] = make_float4(o[4], o[5], o[6], o[7]);
    }
}

// ---------------------------------------------------------------------------
extern "C" void kernel_launch(void* const* d_in, const int* in_sizes, int n_in,
                              void* d_out, int out_size, void* d_ws, size_t ws_size,
                              hipStream_t stream)
{
    const float* x     = (const float*)d_in[0];
    const int*   ei    = (const int*)d_in[1];
    const float* W1    = (const float*)d_in[2];
    const float* attS1 = (const float*)d_in[3];
    const float* attD1 = (const float*)d_in[4];
    const float* b1    = (const float*)d_in[5];
    const float* W2    = (const float*)d_in[6];
    const float* attS2 = (const float*)d_in[7];
    const float* attD2 = (const float*)d_in[8];
    const float* b2    = (const float*)d_in[9];

    const int E = in_sizes[1] / 2;
    const int* src = ei;
    const int* dst = ei + E;

    float* out = (float*)d_out;
    float* f = (float*)d_ws;
    float* aS1  = f;  f += (size_t)N_NODES * 8;
    float* aD1  = f;  f += (size_t)N_NODES * 8;
    float* a2s  = f;  f += (size_t)N_NODES;
    float* a2d  = f;  f += (size_t)N_NODES;
    unsigned short* h1b = (unsigned short*)f;  f += (size_t)N_NODES * 32;  // bf16 [N][64]
    unsigned short* h2b = (unsigned short*)f;  f += (size_t)N_NODES * 20 + 64;  // bf16 [N][40] (+pad)
    short* bph = (short*)f;  f += 16384;        // 512*64 shorts (64 KB)
    short* bpl = (short*)f;  f += 16384;
    unsigned int* pairs = (unsigned int*)f;  f += (size_t)NB * CAP;
    int* ip = (int*)f;
    int* coarseCur = ip;  ip += 256;
    int* cumS      = ip;  ip += N_NODES;
    int* cumE      = ip;  ip += N_NODES;
    int* ssrc      = ip;  ip += (size_t)NB * CAP;

    const int partBlocks = (E + TILE - 1) / TILE;

    // cursors zeroed (part adds the b*CAP base locally)
    hipMemsetAsync(coarseCur, 0, 256 * sizeof(int), stream);

    // ---- phase 1: packW || coarse partition (independent roles, one launch)
    k_pre<<<PACKW_BLOCKS + partBlocks, 256, 0, stream>>>(W1, bph, bpl,
                                                         src, dst, E, coarseCur, pairs);

    // ---- phase 2: fine scatter (first) || gemm1 (staged MFMA)
    k_mid<<<NB + GEMM1_BLOCKS, 256, 0, stream>>>(x, bph, bpl, attS1, attD1,
                                                 h1b, aS1, aD1,
                                                 coarseCur, pairs, ssrc, cumS, cumE);

    // ---- layer-1 aggregation fused with layer-2 GEMM + logits
    k_agg1f<<<N_NODES / 4, 256, 0, stream>>>(cumS, cumE, ssrc, aS1, aD1, h1b, b1,
                                             W2, attS2, attD2, h2b, a2s, a2d);

    // ---- layer-2 aggregation
    k_agg2<<<N_NODES / 4, 256, 0, stream>>>(cumS, cumE, ssrc, a2s, a2d, h2b, b2, out);
}